// Round 4
// baseline (449.630 us; speedup 1.0000x reference)
//
#include <hip/hip_runtime.h>

// out[i] = sum_{e: rows[e]==i} Param_W[params[e]] * x[cols[e]] + Param_b[b_params[i]]
// N = 262144, E = 16777216, NPARAMS = 1280, NB = 16.
//
// R4: counting-sort restructure. Kernel C partitions each block's 16384 edges
// into 8 slice-bins inside a private pair region (ballot-compacted writes, no
// device atomics). Kernel D streams each bin's pairs coalescedly into a 128 KiB
// LDS accumulator. Kernel E reduces 32 partials/slice + bias.

#define SLICE_BITS  15
#define SLICE_SIZE  (1 << SLICE_BITS)   // 32768
#define SLICES      8
#define ACC_CHUNKS  32                  // partial copies per slice
#define NPARAMS_MAX 2048

#define SC_BLOCKS   1024
#define SC_THREADS  256
#define EPB         16384               // edges per scatter block
#define GPB         (EPB / 4)           // 4096 int4 groups per block
#define TILES       8
#define TILE_G      (GPB / TILES)       // 512 groups per tile (2 per thread)

// ---------------- Kernel C: histogram + bin-partition scatter ----------------
template<bool PACKED>
__global__ __launch_bounds__(SC_THREADS) void scatter_kernel(
    const float* __restrict__ x, const float* __restrict__ PW, int nparams,
    const int4* __restrict__ rows4, const int4* __restrict__ cols4,
    const int4* __restrict__ params4,
    void* __restrict__ pairs_v, int* __restrict__ ofs)
{
    __shared__ float pw_lds[NPARAMS_MAX];
    __shared__ int ihist[8];
    __shared__ int sbase[8];
    __shared__ int cursor[8];

    const int blk = blockIdx.x;
    const int tid = threadIdx.x;
    if (tid < 8) ihist[tid] = 0;
    for (int j = tid; j < nparams; j += SC_THREADS) pw_lds[j] = PW[j];
    __syncthreads();

    const int4* rp = rows4   + (size_t)blk * GPB;
    const int4* cp = cols4   + (size_t)blk * GPB;
    const int4* pp = params4 + (size_t)blk * GPB;

    // pass 1: per-thread 8-bin counts packed in one 64-bit (64 edges/thread, max 64/bin)
    unsigned long long c64 = 0;
#pragma unroll
    for (int i = 0; i < GPB / SC_THREADS; ++i) {   // 16 int4 groups
        const int4 r = rp[i * SC_THREADS + tid];
        c64 += 1ULL << ((r.x >> SLICE_BITS) * 8);
        c64 += 1ULL << ((r.y >> SLICE_BITS) * 8);
        c64 += 1ULL << ((r.z >> SLICE_BITS) * 8);
        c64 += 1ULL << ((r.w >> SLICE_BITS) * 8);
    }
#pragma unroll
    for (int b = 0; b < 8; ++b) {
        const int c = (int)((c64 >> (b * 8)) & 0xFF);
        if (c) atomicAdd(&ihist[b], c);
    }
    __syncthreads();
    if (tid == 0) {
        int run = 0;
#pragma unroll
        for (int b = 0; b < 8; ++b) { sbase[b] = run; cursor[b] = run; run += ihist[b]; }
    }
    __syncthreads();
    if (tid < 8) ofs[blk * 8 + tid] = sbase[tid];

    const int lane = tid & 63;
    const unsigned long long lt = (1ULL << lane) - 1ULL;

    // pass 2: compute values, ballot-compact into bin-grouped private region
    for (int t = 0; t < TILES; ++t) {
        const int g0 = t * TILE_G + tid;
        const int g1 = g0 + SC_THREADS;
        const int4 r0 = rp[g0], r1 = rp[g1];
        const int4 c0 = cp[g0], c1 = cp[g1];
        const int4 p0 = pp[g0], p1 = pp[g1];
        const int e[8]  = { r0.x, r0.y, r0.z, r0.w, r1.x, r1.y, r1.z, r1.w };
        const int cc[8] = { c0.x, c0.y, c0.z, c0.w, c1.x, c1.y, c1.z, c1.w };
        const int pq[8] = { p0.x, p0.y, p0.z, p0.w, p1.x, p1.y, p1.z, p1.w };
        float v[8];
#pragma unroll
        for (int j = 0; j < 8; ++j) v[j] = pw_lds[pq[j]] * x[cc[j]];
#pragma unroll
        for (int j = 0; j < 8; ++j) {
            const int b   = e[j] >> SLICE_BITS;
            const int r15 = e[j] & (SLICE_SIZE - 1);
#pragma unroll
            for (int B = 0; B < 8; ++B) {
                const unsigned long long m = __ballot(b == B);
                if (m == 0) continue;                       // wave-uniform
                const int leader = __ffsll((unsigned long long)m) - 1;
                int base = 0;
                if (lane == leader) base = atomicAdd(&cursor[B], __popcll(m));
                base = __shfl(base, leader);
                if (b == B) {
                    const size_t dst = (size_t)blk * EPB + base + __popcll(m & lt);
                    if (PACKED) {
                        const unsigned int u =
                            (__float_as_uint(v[j]) + 0x8000u) & 0xFFFF0000u;
                        ((unsigned int*)pairs_v)[dst] = u | (unsigned int)r15;
                    } else {
                        ((int2*)pairs_v)[dst] = make_int2(r15, __float_as_int(v[j]));
                    }
                }
            }
        }
    }
}

// ---------------- Kernel D: per-slice streaming accumulate ----------------
template<bool PACKED>
__global__ __launch_bounds__(1024, 1) void accum_kernel(
    const void* __restrict__ pairs_v, const int* __restrict__ ofs,
    float* __restrict__ partials)
{
    __shared__ float acc[SLICE_SIZE];   // 128 KiB
    const int B = blockIdx.x >> 5;      // slice
    const int k = blockIdx.x & 31;      // chunk of source blocks
    for (int j = threadIdx.x; j < SLICE_SIZE; j += 1024) acc[j] = 0.0f;
    __syncthreads();
    for (int blk = k * 32; blk < k * 32 + 32; ++blk) {
        const int o   = ofs[blk * 8 + B];
        const int end = (B == 7) ? EPB : ofs[blk * 8 + B + 1];
        const size_t base = (size_t)blk * EPB;
        if (PACKED) {
            const unsigned int* p = (const unsigned int*)pairs_v;
            for (int i = o + (int)threadIdx.x; i < end; i += 1024) {
                const unsigned int u = p[base + i];
                atomicAdd(&acc[u & (SLICE_SIZE - 1)], __uint_as_float(u & 0xFFFF0000u));
            }
        } else {
            const int2* p = (const int2*)pairs_v;
            for (int i = o + (int)threadIdx.x; i < end; i += 1024) {
                const int2 q = p[base + i];
                atomicAdd(&acc[q.x], __int_as_float(q.y));
            }
        }
    }
    __syncthreads();
    float* dst = partials + (size_t)blockIdx.x * SLICE_SIZE;
    for (int j = threadIdx.x; j < SLICE_SIZE; j += 1024) dst[j] = acc[j];
}

// ---------------- Kernel E: reduce partials + bias ----------------
__global__ __launch_bounds__(256) void reduce_bias_kernel(
    const float* __restrict__ partials, const float* __restrict__ Pb,
    const int* __restrict__ bp, float* __restrict__ out, int n)
{
    const int i = blockIdx.x * 256 + threadIdx.x;
    if (i >= n) return;
    const int s = i >> SLICE_BITS;
    const int j = i & (SLICE_SIZE - 1);
    const float* p = partials + ((size_t)s * ACC_CHUNKS) * SLICE_SIZE + j;
    float sum = 0.0f;
#pragma unroll
    for (int g = 0; g < ACC_CHUNKS; ++g) sum += p[(size_t)g * SLICE_SIZE];
    out[i] = sum + Pb[bp[i]];
}

// ---------------- fallback: R3 slice-scan path ----------------
#define FB_CHUNKS 32
#define FB_THREADS 1024
#define FB_BATCH 4

__global__ __launch_bounds__(FB_THREADS, 1) void slice_scan_kernel(
    const float* __restrict__ x, const float* __restrict__ PW, int nparams,
    const int4* __restrict__ rows4, const int4* __restrict__ cols4,
    const int4* __restrict__ params4, float* __restrict__ partials,
    int e4_per_chunk)
{
    __shared__ float acc[SLICE_SIZE];
    __shared__ float pw_lds[NPARAMS_MAX];
    const int bid = blockIdx.x;
    const int s = bid / FB_CHUNKS;
    const int c = bid % FB_CHUNKS;
    for (int j = threadIdx.x; j < SLICE_SIZE; j += FB_THREADS) acc[j] = 0.0f;
    for (int j = threadIdx.x; j < nparams; j += FB_THREADS) pw_lds[j] = PW[j];
    __syncthreads();
    const int4* rp = rows4   + (size_t)c * e4_per_chunk;
    const int4* cp = cols4   + (size_t)c * e4_per_chunk;
    const int4* qp = params4 + (size_t)c * e4_per_chunk;
    const int per_thread = e4_per_chunk / FB_THREADS;
    for (int base = 0; base < per_thread; base += FB_BATCH) {
        int4 r[FB_BATCH], cc[FB_BATCH], pp[FB_BATCH];
#pragma unroll
        for (int b = 0; b < FB_BATCH; ++b) {
            const int g = (base + b) * FB_THREADS + threadIdx.x;
            r[b] = rp[g]; cc[b] = cp[g]; pp[b] = qp[g];
        }
#pragma unroll
        for (int b = 0; b < FB_BATCH; ++b) {
            if ((r[b].x >> SLICE_BITS) == s)
                atomicAdd(&acc[r[b].x & (SLICE_SIZE - 1)], pw_lds[pp[b].x] * x[cc[b].x]);
            if ((r[b].y >> SLICE_BITS) == s)
                atomicAdd(&acc[r[b].y & (SLICE_SIZE - 1)], pw_lds[pp[b].y] * x[cc[b].y]);
            if ((r[b].z >> SLICE_BITS) == s)
                atomicAdd(&acc[r[b].z & (SLICE_SIZE - 1)], pw_lds[pp[b].z] * x[cc[b].z]);
            if ((r[b].w >> SLICE_BITS) == s)
                atomicAdd(&acc[r[b].w & (SLICE_SIZE - 1)], pw_lds[pp[b].w] * x[cc[b].w]);
        }
    }
    __syncthreads();
    float* dst = partials + (size_t)bid * SLICE_SIZE;
    for (int j = threadIdx.x; j < SLICE_SIZE; j += FB_THREADS) dst[j] = acc[j];
}

__global__ __launch_bounds__(256) void bias_init_kernel(const float* __restrict__ Pb,
                                                        const int* __restrict__ bp,
                                                        float* __restrict__ out, int n) {
    int i = blockIdx.x * 256 + threadIdx.x;
    if (i < n) out[i] = Pb[bp[i]];
}

__global__ __launch_bounds__(256) void edge_scatter_kernel(const float* __restrict__ x,
                                                           const float* __restrict__ PW,
                                                           const int* __restrict__ rows,
                                                           const int* __restrict__ cols,
                                                           const int* __restrict__ params,
                                                           float* __restrict__ out, int E) {
    int e = blockIdx.x * 256 + threadIdx.x;
    if (e < E) atomicAdd(out + rows[e], PW[params[e]] * x[cols[e]]);
}

extern "C" void kernel_launch(void* const* d_in, const int* in_sizes, int n_in,
                              void* d_out, int out_size, void* d_ws, size_t ws_size,
                              hipStream_t stream) {
    const float* x        = (const float*)d_in[0];
    const float* Param_W  = (const float*)d_in[1];
    const float* Param_b  = (const float*)d_in[2];
    const int*   w_rows   = (const int*)d_in[3];
    const int*   w_cols   = (const int*)d_in[4];
    const int*   w_params = (const int*)d_in[5];
    const int*   b_params = (const int*)d_in[6];
    float* out = (float*)d_out;

    const int N_  = in_sizes[0];   // 262144
    const int NP_ = in_sizes[1];   // 1280
    const int E_  = in_sizes[3];   // 16777216

    const size_t partial_bytes = (size_t)SLICES * ACC_CHUNKS * SLICE_SIZE * sizeof(float); // 32 MiB
    const size_t ofs_bytes     = (size_t)SC_BLOCKS * 8 * sizeof(int);                       // 32 KiB
    const bool shapes_ok = (N_ == SLICES * SLICE_SIZE) && (E_ == SC_BLOCKS * EPB) &&
                           (NP_ <= NPARAMS_MAX);
    const size_t need_fp32   = (size_t)E_ * 8 + ofs_bytes + partial_bytes;
    const size_t need_packed = (size_t)E_ * 4 + ofs_bytes + partial_bytes;

    if (shapes_ok && ws_size >= need_fp32) {
        void* pairs    = d_ws;
        int*  ofs      = (int*)((char*)d_ws + (size_t)E_ * 8);
        float* partials = (float*)((char*)d_ws + (size_t)E_ * 8 + ofs_bytes);
        scatter_kernel<false><<<SC_BLOCKS, SC_THREADS, 0, stream>>>(
            x, Param_W, NP_, (const int4*)w_rows, (const int4*)w_cols,
            (const int4*)w_params, pairs, ofs);
        accum_kernel<false><<<SLICES * ACC_CHUNKS, 1024, 0, stream>>>(pairs, ofs, partials);
        reduce_bias_kernel<<<(N_ + 255) / 256, 256, 0, stream>>>(
            partials, Param_b, b_params, out, N_);
    } else if (shapes_ok && ws_size >= need_packed) {
        void* pairs    = d_ws;
        int*  ofs      = (int*)((char*)d_ws + (size_t)E_ * 4);
        float* partials = (float*)((char*)d_ws + (size_t)E_ * 4 + ofs_bytes);
        scatter_kernel<true><<<SC_BLOCKS, SC_THREADS, 0, stream>>>(
            x, Param_W, NP_, (const int4*)w_rows, (const int4*)w_cols,
            (const int4*)w_params, pairs, ofs);
        accum_kernel<true><<<SLICES * ACC_CHUNKS, 1024, 0, stream>>>(pairs, ofs, partials);
        reduce_bias_kernel<<<(N_ + 255) / 256, 256, 0, stream>>>(
            partials, Param_b, b_params, out, N_);
    } else if ((N_ == SLICES * SLICE_SIZE) &&
               (E_ % (4 * FB_CHUNKS * FB_THREADS * FB_BATCH) == 0) &&
               (NP_ <= NPARAMS_MAX) && ws_size >= partial_bytes) {
        float* partials = (float*)d_ws;
        const int e4_per_chunk = E_ / 4 / FB_CHUNKS;
        slice_scan_kernel<<<SLICES * FB_CHUNKS, FB_THREADS, 0, stream>>>(
            x, Param_W, NP_, (const int4*)w_rows, (const int4*)w_cols,
            (const int4*)w_params, partials, e4_per_chunk);
        reduce_bias_kernel<<<(N_ + 255) / 256, 256, 0, stream>>>(
            partials, Param_b, b_params, out, N_);
    } else {
        bias_init_kernel<<<(N_ + 255) / 256, 256, 0, stream>>>(Param_b, b_params, out, N_);
        edge_scatter_kernel<<<(E_ + 255) / 256, 256, 0, stream>>>(
            x, Param_W, w_rows, w_cols, w_params, out, E_);
    }
}